// Round 3
// baseline (838.898 us; speedup 1.0000x reference)
//
#include <hip/hip_runtime.h>
#include <hip/hip_bf16.h>
#include <math.h>

// Problem constants (fixed by setup_inputs)
#define B_ 2
#define N_ 4096
#define D_ 2048
#define H_ 16
#define DH_ 128
#define CHUNK_ 256
#define NC_ 16
#define M_ (B_*N_)          // 8192 tokens
#define F3D (3*D_)          // 6144

typedef __bf16 v8bf __attribute__((ext_vector_type(8)));
typedef float  v4f  __attribute__((ext_vector_type(4)));

__device__ __forceinline__ void async_copy16(void* lds, const void* g) {
    __builtin_amdgcn_global_load_lds(
        (const __attribute__((address_space(1))) unsigned int*)g,
        (__attribute__((address_space(3))) unsigned int*)lds,
        16, 0, 0);
}

// ---------------- RMSNorm: x (f32) -> xn (bf16) ----------------
__global__ __launch_bounds__(256) void k_rmsnorm(const float* __restrict__ x,
                                                 const float* __restrict__ scale,
                                                 __hip_bfloat16* __restrict__ xn)
{
    __shared__ float red[4];
    const int row = blockIdx.x;
    const float* xr = x + (size_t)row * D_;
    float ss = 0.f;
    const float4* x4 = (const float4*)xr;
    for (int i = threadIdx.x; i < D_/4; i += 256) {
        float4 v = x4[i];
        ss += v.x*v.x + v.y*v.y + v.z*v.z + v.w*v.w;
    }
    #pragma unroll
    for (int off = 32; off > 0; off >>= 1) ss += __shfl_down(ss, off, 64);
    if ((threadIdx.x & 63) == 0) red[threadIdx.x >> 6] = ss;
    __syncthreads();
    float tot = red[0] + red[1] + red[2] + red[3];
    float r = rsqrtf(tot / (float)D_ + 1e-6f);
    for (int i = threadIdx.x; i < D_; i += 256) {
        float v = scale[i] * xr[i] * r;
        v = fminf(fmaxf(v, -60000.f), 60000.f);
        xn[(size_t)row * D_ + i] = __float2bfloat16(v);
    }
}

// ---------------- depthwise causal conv (K=4) + SiLU ----------------
__global__ __launch_bounds__(256) void k_conv_silu(const __hip_bfloat16* __restrict__ xn,
                                                   const float* __restrict__ w,
                                                   const float* __restrict__ bias,
                                                   __hip_bfloat16* __restrict__ xc)
{
    size_t idx = (size_t)blockIdx.x * 256 + threadIdx.x;   // over B*N*D
    int d = (int)(idx & (D_-1));
    int n = (int)((idx >> 11) & (N_-1));
    float acc = bias[d];
    #pragma unroll
    for (int k = 0; k < 4; ++k) {
        int nn = n - 3 + k;
        if (nn >= 0)
            acc += __bfloat162float(xn[idx - (size_t)(3-k) * D_]) * w[d*4 + k];
    }
    float sig = 1.f / (1.f + expf(-acc));
    xc[idx] = __float2bfloat16(acc * sig);
}

// ---------------- f32 -> bf16 cast (weights) ----------------
__global__ __launch_bounds__(256) void k_cast_bf16(const float* __restrict__ src,
                                                   __hip_bfloat16* __restrict__ dst, size_t n)
{
    size_t stride = (size_t)gridDim.x * 256;
    for (size_t i = (size_t)blockIdx.x * 256 + threadIdx.x; i < n; i += stride)
        dst[i] = __float2bfloat16(src[i]);
}

// ---------------- bf16 NT GEMM: acc[m][n] = sum_k A[m][k] * W[n][k] ----------------
// 128x128 tile, BK=32, 4 waves (2x2 quadrants of 64x64), mfma_f32_16x16x32_bf16
// MODE 0: in_proj  — route 2048-wide column streams: 0 -> o0 (f32 dt_raw),
//                    1 -> o1 (f32 v), 2 -> sigmoid -> o2 (bf16 gate). ld = 2048.
// MODE 1: out_proj — out[off] = acc + resid[off], Nn = 2048.
template<int MODE>
__global__ __launch_bounds__(256) void k_gemm(const __hip_bfloat16* __restrict__ Abf,
                                              const __hip_bfloat16* __restrict__ Wbf,
                                              int K,
                                              float* __restrict__ o0,
                                              float* __restrict__ o1,
                                              __hip_bfloat16* __restrict__ o2,
                                              const float* __restrict__ resid,
                                              float* __restrict__ outp)
{
    __shared__ __attribute__((aligned(16))) __bf16 As[128*32];
    __shared__ __attribute__((aligned(16))) __bf16 Bs[128*32];
    const __bf16* A = (const __bf16*)Abf;
    const __bf16* W = (const __bf16*)Wbf;
    const int tid  = threadIdx.x;
    const int wave = tid >> 6;
    const int lane = tid & 63;
    const size_t m0 = (size_t)blockIdx.x * 128;
    const size_t n0 = (size_t)blockIdx.y * 128;
    const int wm = (wave & 1) * 64;
    const int wn = (wave >> 1) * 64;

    v4f acc[4][4] = {};

    const int fr = lane & 15;          // fragment row within 16x16
    const int kc = (lane >> 4) * 8;    // k-chunk (8 bf16)
    const int ldrow = lane >> 2;       // staging: 16 rows per call
    const int ldk   = (lane & 3) * 8;  // staging: 8 bf16 per lane

    const int kIters = K >> 5;
    for (int kt = 0; kt < kIters; ++kt) {
        const int k0 = kt << 5;
        __syncthreads();   // protect LDS from previous iteration's readers
        #pragma unroll
        for (int cc = 0; cc < 2; ++cc) {
            int row = wave*32 + cc*16 + ldrow;
            int kof = k0 + ldk;
            async_copy16((void*)(As + (wave*32 + cc*16)*32),
                         (const void*)(A + (m0 + row)*(size_t)K + kof));
            async_copy16((void*)(Bs + (wave*32 + cc*16)*32),
                         (const void*)(W + (n0 + row)*(size_t)K + kof));
        }
        __syncthreads();   // drains vmcnt before barrier -> staging visible

        v8bf fa[4], fb[4];
        #pragma unroll
        for (int i = 0; i < 4; ++i) {
            fa[i] = *(const v8bf*)(As + (wm + i*16 + fr)*32 + kc);
            fb[i] = *(const v8bf*)(Bs + (wn + i*16 + fr)*32 + kc);
        }
        #pragma unroll
        for (int i = 0; i < 4; ++i)
            #pragma unroll
            for (int j = 0; j < 4; ++j)
                acc[i][j] = __builtin_amdgcn_mfma_f32_16x16x32_bf16(fa[i], fb[j], acc[i][j], 0, 0, 0);
    }

    // epilogue: C/D layout col=lane&15, row=(lane>>4)*4+r  (m89-verified)
    const int col = lane & 15;
    const int rb  = (lane >> 4) * 4;
    if (MODE == 0) {
        const int stream = blockIdx.y >> 4;                 // 2048/128 = 16 blocks/stream
        const size_t nb = n0 - (size_t)stream * D_;
        #pragma unroll
        for (int i = 0; i < 4; ++i)
            #pragma unroll
            for (int j = 0; j < 4; ++j)
                #pragma unroll
                for (int r = 0; r < 4; ++r) {
                    size_t m = m0 + wm + i*16 + rb + r;
                    size_t off = m * (size_t)D_ + nb + wn + j*16 + col;
                    float v = acc[i][j][r];
                    if (stream == 0)      o0[off] = v;
                    else if (stream == 1) o1[off] = v;
                    else                  o2[off] = __float2bfloat16(1.f / (1.f + expf(-v)));
                }
    } else {
        #pragma unroll
        for (int i = 0; i < 4; ++i)
            #pragma unroll
            for (int j = 0; j < 4; ++j)
                #pragma unroll
                for (int r = 0; r < 4; ++r) {
                    size_t m = m0 + wm + i*16 + rb + r;
                    size_t off = m * (size_t)D_ + n0 + wn + j*16 + col;
                    outp[off] = acc[i][j][r] + resid[off];
                }
    }
}

// ---------------- elementwise: dt/softplus (in place on la), RoPE*dt (in place on v) ----------------
__global__ __launch_bounds__(256) void k_elemwise(float* __restrict__ la,
                                                  float* __restrict__ v,
                                                  const float* __restrict__ dt_bias)
{
    const size_t stride = (size_t)gridDim.x * 256;
    const size_t P = (size_t)M_ * (D_/2);
    for (size_t p = (size_t)blockIdx.x*256 + threadIdx.x; p < P; p += stride) {
        int rem = (int)(p & 1023);          // D/2 = 1024
        size_t row = p >> 10;
        int h = rem >> 6;                    // head
        int i = rem & 63;                    // rotary pair index
        int d1 = h * DH_ + i;
        int d2 = d1 + 64;
        int n = (int)(row & (N_-1));
        size_t base = row * (size_t)D_;

        float x1 = la[base + d1] + dt_bias[d1];
        float x2 = la[base + d2] + dt_bias[d2];
        float sp1 = fmaxf(x1, 0.f) + log1pf(expf(-fabsf(x1)));
        float sp2 = fmaxf(x2, 0.f) + log1pf(expf(-fabsf(x2)));
        float dt1 = fminf(fmaxf(sp1, 0.001f), 2.0f);
        float dt2 = fminf(fmaxf(sp2, 0.001f), 2.0f);

        float inv = expf((float)i * (-9.210340371976184f / 64.f)); // 10000^(-i/64)
        float ang = (float)n * inv;
        float c = cosf(ang), s = sinf(ang);
        float v1 = v[base + d1];
        float v2 = v[base + d2];
        float r1 = v1*c - v2*s;
        float r2 = v1*s + v2*c;

        la[base + d1] = -dt1;                // log_alpha
        la[base + d2] = -dt2;
        v[base + d1] = r1 * dt1;             // v_in
        v[base + d2] = r2 * dt2;
    }
}

// ---------------- scan phase 1: per (b,chunk,d) -> bd (last L), bo (last out) ----------------
__global__ __launch_bounds__(256) void k_scan1(const float* __restrict__ la,
                                               const float* __restrict__ v,
                                               float* __restrict__ bd, float* __restrict__ bo)
{
    int idx = blockIdx.x * 256 + threadIdx.x;   // B*NC*D = 65536
    int d = idx & (D_-1);
    int c = (idx >> 11) & (NC_-1);
    int b = idx >> 15;
    size_t row0 = (size_t)b * N_ + (size_t)c * CHUNK_;
    float S = 0.f, Lp = 0.f, out = 0.f;
    #pragma unroll 8
    for (int t = 0; t < CHUNK_; ++t) {
        size_t off = (row0 + t) * (size_t)D_ + d;
        float a = la[off];
        float vv = v[off];
        S += a;
        float L = fmaxf(S, -20.f);           // clip(cumsum,-20,0): upper never binds (la<0)
        out = expf(L - Lp) * out + vv;       // t=0: out=0 -> out=v exactly
        Lp = L;
    }
    bd[idx] = Lp;
    bo[idx] = out;
}

// ---------------- scan phase 2: cross-chunk combine -> carries ----------------
__global__ __launch_bounds__(256) void k_scan2(const float* __restrict__ bd,
                                               const float* __restrict__ bo,
                                               float* __restrict__ carries)
{
    int idx = blockIdx.x * 256 + threadIdx.x;   // B*D = 4096
    int d = idx & (D_-1);
    int b = idx >> 11;
    float bd0 = bd[(size_t)(b*NC_)*D_ + d];     // stab = cd[0] = bd[0] (>= -20)
    float cd = 0.f, acc = 0.f;
    #pragma unroll
    for (int c = 0; c < NC_; ++c) {
        size_t o = (size_t)(b*NC_ + c)*D_ + d;
        cd = fmaxf(cd + bd[o], -80.f);          // clip(cumsum(bd),-80,0); progressive == clip-after (monotone)
        float ncd = fmaxf(cd - bd0, -20.f);     // clip(cd-stab,-20,0); upper never binds
        carries[o] = acc * expf(ncd);           // sum of seeds STRICTLY BEFORE c
        acc += bo[o] * expf(-ncd);
    }
}

// ---------------- scan phase 3: recompute chunk scan + carry; final state over v (in place) ----------------
__global__ __launch_bounds__(256) void k_scan3(const float* __restrict__ la,
                                               float* __restrict__ v,
                                               const float* __restrict__ carries)
{
    int idx = blockIdx.x * 256 + threadIdx.x;
    int d = idx & (D_-1);
    int c = (idx >> 11) & (NC_-1);
    int b = idx >> 15;
    float carry = carries[idx];
    size_t row0 = (size_t)b * N_ + (size_t)c * CHUNK_;
    float S = 0.f, Lp = 0.f, out = 0.f;
    #pragma unroll 8
    for (int t = 0; t < CHUNK_; ++t) {
        size_t off = (row0 + t) * (size_t)D_ + d;
        float a = la[off];
        float vv = v[off];
        S += a;
        float L = fmaxf(S, -20.f);
        out = expf(L - Lp) * out + vv;
        Lp = L;
        v[off] = out + carry * expf(L);       // write after reading
    }
}

// ---------------- head_mix (generic 16x16) * gate -> y (bf16) ----------------
__global__ __launch_bounds__(256) void k_headmix_gate(const float* __restrict__ state,
                                                      const __hip_bfloat16* __restrict__ gate,
                                                      const float* __restrict__ hm,
                                                      __hip_bfloat16* __restrict__ y)
{
    __shared__ float lf[D_];
    __shared__ float lhm[H_*H_];
    const int row = blockIdx.x;
    const size_t base = (size_t)row * D_;
    for (int i = threadIdx.x; i < D_; i += 256) lf[i] = state[base + i];
    if (threadIdx.x < H_*H_) lhm[threadIdx.x] = hm[threadIdx.x];
    __syncthreads();
    for (int o = threadIdx.x; o < D_; o += 256) {
        int m  = o >> 7;
        int dh = o & 127;
        float s = 0.f;
        #pragma unroll
        for (int h = 0; h < H_; ++h) s += lf[h*DH_ + dh] * lhm[h*H_ + m];
        float g = __bfloat162float(gate[base + o]);
        y[base + o] = __float2bfloat16(s * g);
    }
}

extern "C" void kernel_launch(void* const* d_in, const int* in_sizes, int n_in,
                              void* d_out, int out_size, void* d_ws, size_t ws_size,
                              hipStream_t stream)
{
    const float* x          = (const float*)d_in[0];
    const float* norm_scale = (const float*)d_in[1];
    const float* conv_w     = (const float*)d_in[2];
    const float* conv_b     = (const float*)d_in[3];
    const float* in_proj_w  = (const float*)d_in[4];
    const float* dt_bias    = (const float*)d_in[5];
    const float* head_mix   = (const float*)d_in[6];
    const float* out_proj_w = (const float*)d_in[7];
    float* out = (float*)d_out;

    // Workspace layout — total 176,947,200 B.
    // (round-2 bug: gate was sized 16 MB but needs M*D*2 = 33,554,432 B; the
    //  overflow clobbered w2 and made headmix read scan f32 bytes as bf16 -> NaN)
    char* ws = (char*)d_ws;
    float*          la   = (float*)ws;                               // 67,108,864 B (dt_raw -> log_alpha)
    __hip_bfloat16* xn   = (__hip_bfloat16*)(ws + 67108864);         // 33,554,432 B; reused for w1 after conv
    __hip_bfloat16* xc   = (__hip_bfloat16*)(ws + 100663296);        // 33,554,432 B; reused for y after GEMM1
    __hip_bfloat16* gate = (__hip_bfloat16*)(ws + 134217728);        // 33,554,432 B  (FULL size now)
    __hip_bfloat16* w2   = (__hip_bfloat16*)(ws + 167772160);        //  8,388,608 B
    float*          bd   = (float*)(ws + 176160768);                 //    262,144 B
    float*          bo   = (float*)(ws + 176422912);                 //    262,144 B
    float*          carr = (float*)(ws + 176685056);                 //    262,144 B
    __hip_bfloat16* w1   = xn;   // xn dead after conv (w1 = 25,165,824 B <= 33,554,432 B)
    __hip_bfloat16* y    = xc;   // xc dead after GEMM1
    float*          v    = out;  // d_out as scratch: v -> state -> final output (67,108,864 B exactly)

    k_rmsnorm<<<M_, 256, 0, stream>>>(x, norm_scale, xn);
    k_conv_silu<<<(B_*N_*D_)/256, 256, 0, stream>>>(xn, conv_w, conv_b, xc);
    k_cast_bf16<<<2048, 256, 0, stream>>>(in_proj_w, w1, (size_t)F3D * D_);   // after conv (region reuse)
    k_cast_bf16<<<1024, 256, 0, stream>>>(out_proj_w, w2, (size_t)D_ * D_);
    k_gemm<0><<<dim3(M_/128, F3D/128), 256, 0, stream>>>(xc, w1, D_, la, v, gate, nullptr, nullptr);
    k_elemwise<<<4096, 256, 0, stream>>>(la, v, dt_bias);
    k_scan1<<<(B_*NC_*D_)/256, 256, 0, stream>>>(la, v, bd, bo);
    k_scan2<<<(B_*D_)/256, 256, 0, stream>>>(bd, bo, carr);
    k_scan3<<<(B_*NC_*D_)/256, 256, 0, stream>>>(la, v, carr);
    k_headmix_gate<<<M_, 256, 0, stream>>>(v, gate, head_mix, y);
    k_gemm<1><<<dim3(M_/128, D_/128), 256, 0, stream>>>(y, w2, D_, nullptr, nullptr, nullptr, x, out);
}

// Round 4
// 834.863 us; speedup vs baseline: 1.0048x; 1.0048x over previous
//
#include <hip/hip_runtime.h>
#include <hip/hip_bf16.h>
#include <math.h>

// Problem constants (fixed by setup_inputs)
#define B_ 2
#define N_ 4096
#define D_ 2048
#define H_ 16
#define DH_ 128
#define CHUNK_ 256
#define NC_ 16
#define M_ (B_*N_)          // 8192 tokens
#define F3D (3*D_)          // 6144

typedef __bf16 v8bf __attribute__((ext_vector_type(8)));
typedef float  v4f  __attribute__((ext_vector_type(4)));
typedef unsigned short u16x8 __attribute__((ext_vector_type(8)));

__device__ __forceinline__ float bf2f(unsigned short u) {
    union { unsigned int i; float f; } c; c.i = ((unsigned int)u) << 16; return c.f;
}
__device__ __forceinline__ unsigned short f2bf(float f) {
    __hip_bfloat16 h = __float2bfloat16(f);
    return *(unsigned short*)&h;
}

__device__ __forceinline__ void async_copy16(void* lds, const void* g) {
    __builtin_amdgcn_global_load_lds(
        (const __attribute__((address_space(1))) unsigned int*)g,
        (__attribute__((address_space(3))) unsigned int*)lds,
        16, 0, 0);
}

// ---------------- RMSNorm: x (f32) -> xn (bf16), 8 elems/thread ----------------
__global__ __launch_bounds__(256) void k_rmsnorm(const float* __restrict__ x,
                                                 const float* __restrict__ scale,
                                                 __hip_bfloat16* __restrict__ xn)
{
    __shared__ float red[4];
    const int row = blockIdx.x;
    const float4* x4 = (const float4*)(x + (size_t)row * D_);
    float4 a = x4[threadIdx.x*2];
    float4 b = x4[threadIdx.x*2 + 1];
    float ss = a.x*a.x + a.y*a.y + a.z*a.z + a.w*a.w
             + b.x*b.x + b.y*b.y + b.z*b.z + b.w*b.w;
    #pragma unroll
    for (int off = 32; off > 0; off >>= 1) ss += __shfl_down(ss, off, 64);
    if ((threadIdx.x & 63) == 0) red[threadIdx.x >> 6] = ss;
    __syncthreads();
    float tot = red[0] + red[1] + red[2] + red[3];
    float r = rsqrtf(tot / (float)D_ + 1e-6f);
    const float4* s4 = (const float4*)scale;
    float4 sa = s4[threadIdx.x*2];
    float4 sb = s4[threadIdx.x*2 + 1];
    float v[8] = { sa.x*a.x, sa.y*a.y, sa.z*a.z, sa.w*a.w,
                   sb.x*b.x, sb.y*b.y, sb.z*b.z, sb.w*b.w };
    u16x8 o;
    #pragma unroll
    for (int j = 0; j < 8; ++j) {
        float t = fminf(fmaxf(v[j]*r, -60000.f), 60000.f);
        o[j] = f2bf(t);
    }
    ((u16x8*)(xn + (size_t)row * D_))[threadIdx.x] = o;
}

// ---------------- depthwise causal conv (K=4) + SiLU, 8 elems/thread ----------------
__global__ __launch_bounds__(256) void k_conv_silu(const __hip_bfloat16* __restrict__ xn,
                                                   const float* __restrict__ w,
                                                   const float* __restrict__ bias,
                                                   __hip_bfloat16* __restrict__ xc)
{
    size_t p = (size_t)blockIdx.x * 256 + threadIdx.x;  // over M*D/8
    size_t e0 = p * 8;
    int d0 = (int)(e0 & (D_-1));
    int n  = (int)((e0 >> 11) & (N_-1));
    const float4* w4 = (const float4*)w;               // w4[d] = weights of channel d
    float acc[8];
    const float4* b4 = (const float4*)(bias + d0);
    float4 ba = b4[0], bb = b4[1];
    acc[0]=ba.x; acc[1]=ba.y; acc[2]=ba.z; acc[3]=ba.w;
    acc[4]=bb.x; acc[5]=bb.y; acc[6]=bb.z; acc[7]=bb.w;
    float4 wv[8];
    #pragma unroll
    for (int j = 0; j < 8; ++j) wv[j] = w4[d0 + j];
    #pragma unroll
    for (int k = 0; k < 4; ++k) {
        int nn = n - 3 + k;
        if (nn >= 0) {
            u16x8 t = *(const u16x8*)(xn + e0 - (size_t)(3-k)*D_);
            #pragma unroll
            for (int j = 0; j < 8; ++j) {
                float wk = (k==0)?wv[j].x:(k==1)?wv[j].y:(k==2)?wv[j].z:wv[j].w;
                acc[j] += bf2f(t[j]) * wk;
            }
        }
    }
    u16x8 o;
    #pragma unroll
    for (int j = 0; j < 8; ++j) {
        float s = acc[j] / (1.f + expf(-acc[j]));
        o[j] = f2bf(s);
    }
    *(u16x8*)(xc + e0) = o;
}

// ---------------- f32 -> bf16 cast (weights), 8 elems/thread ----------------
__global__ __launch_bounds__(256) void k_cast_bf16(const float* __restrict__ src,
                                                   __hip_bfloat16* __restrict__ dst)
{
    size_t p = (size_t)blockIdx.x * 256 + threadIdx.x;
    const float4* s4 = (const float4*)src;
    float4 a = s4[p*2], b = s4[p*2 + 1];
    u16x8 o;
    o[0]=f2bf(a.x); o[1]=f2bf(a.y); o[2]=f2bf(a.z); o[3]=f2bf(a.w);
    o[4]=f2bf(b.x); o[5]=f2bf(b.y); o[6]=f2bf(b.z); o[7]=f2bf(b.w);
    ((u16x8*)dst)[p] = o;
}

// ---------------- bf16 NT GEMM: acc[m][n] = sum_k A[m][k] * W[n][k] ----------------
// 128x128 tile, BK=32, 4 waves (2x2 quadrants of 64x64), mfma_f32_16x16x32_bf16
// MODE 0: in_proj — stream 0: la = -clip(softplus(acc+dt_bias[n]),0.001,2) (f32)
//                   stream 1: v raw (bf16);  stream 2: sigmoid -> gate (bf16)
// MODE 1: out_proj — out[off] = acc + resid[off]  (f32)
template<int MODE>
__global__ __launch_bounds__(256) void k_gemm(const __hip_bfloat16* __restrict__ Abf,
                                              const __hip_bfloat16* __restrict__ Wbf,
                                              int K,
                                              float* __restrict__ o0,
                                              __hip_bfloat16* __restrict__ o1,
                                              __hip_bfloat16* __restrict__ o2,
                                              const float* __restrict__ dt_bias,
                                              const float* __restrict__ resid,
                                              float* __restrict__ outp)
{
    __shared__ __attribute__((aligned(16))) __bf16 As[128*32];
    __shared__ __attribute__((aligned(16))) __bf16 Bs[128*32];
    const __bf16* A = (const __bf16*)Abf;
    const __bf16* W = (const __bf16*)Wbf;
    const int tid  = threadIdx.x;
    const int wave = tid >> 6;
    const int lane = tid & 63;
    const size_t m0 = (size_t)blockIdx.x * 128;
    const size_t n0 = (size_t)blockIdx.y * 128;
    const int wm = (wave & 1) * 64;
    const int wn = (wave >> 1) * 64;

    v4f acc[4][4] = {};

    const int fr = lane & 15;          // fragment row within 16x16
    const int kc = (lane >> 4) * 8;    // k-chunk (8 bf16)
    const int ldrow = lane >> 2;       // staging: 16 rows per call
    const int ldk   = (lane & 3) * 8;  // staging: 8 bf16 per lane

    const int kIters = K >> 5;
    for (int kt = 0; kt < kIters; ++kt) {
        const int k0 = kt << 5;
        __syncthreads();
        #pragma unroll
        for (int cc = 0; cc < 2; ++cc) {
            int row = wave*32 + cc*16 + ldrow;
            int kof = k0 + ldk;
            async_copy16((void*)(As + (wave*32 + cc*16)*32),
                         (const void*)(A + (m0 + row)*(size_t)K + kof));
            async_copy16((void*)(Bs + (wave*32 + cc*16)*32),
                         (const void*)(W + (n0 + row)*(size_t)K + kof));
        }
        __syncthreads();

        v8bf fa[4], fb[4];
        #pragma unroll
        for (int i = 0; i < 4; ++i) {
            fa[i] = *(const v8bf*)(As + (wm + i*16 + fr)*32 + kc);
            fb[i] = *(const v8bf*)(Bs + (wn + i*16 + fr)*32 + kc);
        }
        #pragma unroll
        for (int i = 0; i < 4; ++i)
            #pragma unroll
            for (int j = 0; j < 4; ++j)
                acc[i][j] = __builtin_amdgcn_mfma_f32_16x16x32_bf16(fa[i], fb[j], acc[i][j], 0, 0, 0);
    }

    // epilogue: C/D layout col=lane&15, row=(lane>>4)*4+r  (m89-verified)
    const int col = lane & 15;
    const int rb  = (lane >> 4) * 4;
    if (MODE == 0) {
        const int stream = blockIdx.y >> 4;                 // 2048/128 = 16 blocks/stream
        const size_t nb = n0 - (size_t)stream * D_;
        #pragma unroll
        for (int i = 0; i < 4; ++i)
            #pragma unroll
            for (int j = 0; j < 4; ++j) {
                size_t nIdx = nb + wn + j*16 + col;
                #pragma unroll
                for (int r = 0; r < 4; ++r) {
                    size_t m = m0 + wm + i*16 + rb + r;
                    size_t off = m * (size_t)D_ + nIdx;
                    float v = acc[i][j][r];
                    if (stream == 0) {
                        float xx = v + dt_bias[nIdx];
                        float sp = fmaxf(xx, 0.f) + log1pf(expf(-fabsf(xx)));
                        float dt = fminf(fmaxf(sp, 0.001f), 2.0f);
                        o0[off] = -dt;                                  // log_alpha
                    } else if (stream == 1) {
                        o1[off] = __float2bfloat16(v);                  // raw v
                    } else {
                        o2[off] = __float2bfloat16(1.f/(1.f+expf(-v))); // gate
                    }
                }
            }
    } else {
        #pragma unroll
        for (int i = 0; i < 4; ++i)
            #pragma unroll
            for (int j = 0; j < 4; ++j)
                #pragma unroll
                for (int r = 0; r < 4; ++r) {
                    size_t m = m0 + wm + i*16 + rb + r;
                    size_t off = m * (size_t)D_ + n0 + wn + j*16 + col;
                    outp[off] = acc[i][j][r] + resid[off];
                }
    }
}

// ---------------- scan phase 1: RoPE*dt fused; per (b,chunk,d) -> bd, bo ----------------
__global__ __launch_bounds__(256) void k_scan1(const float* __restrict__ la,
                                               const __hip_bfloat16* __restrict__ v,
                                               float* __restrict__ bd, float* __restrict__ bo)
{
    int idx = blockIdx.x * 256 + threadIdx.x;   // B*NC*D = 65536
    int d = idx & (D_-1);
    int c = (idx >> 11) & (NC_-1);
    int b = idx >> 15;
    int i = d & 63;
    const bool firstHalf = (d & 64) == 0;
    float inv = expf((float)i * (-9.210340371976184f / 64.f)); // 10000^(-i/64)
    int n0 = c * CHUNK_;
    // incremental rotation: (cs,sn) = (cos,sin)(n*inv), step by inv
    float cs = cosf((float)n0 * inv), sn = sinf((float)n0 * inv);
    float ca = cosf(inv), sa = sinf(inv);
    size_t row0 = (size_t)b * N_ + (size_t)c * CHUNK_;
    float S = 0.f, Lp = 0.f, out = 0.f;
    #pragma unroll 8
    for (int t = 0; t < CHUNK_; ++t) {
        size_t off = (row0 + t) * (size_t)D_ + d;
        float a  = la[off];
        float vo = __bfloat162float(v[off]);
        float vp = __bfloat162float(v[firstHalf ? off + 64 : off - 64]);
        float dt = -a;
        float vin = (firstHalf ? (vo*cs - vp*sn) : (vp*sn + vo*cs)) * dt;
        S += a;
        float L = fmaxf(S, -20.f);           // clip(cumsum,-20,0): upper never binds
        out = expf(L - Lp) * out + vin;
        Lp = L;
        float csn = cs*ca - sn*sa;           // advance angle by inv
        sn = sn*ca + cs*sa;
        cs = csn;
    }
    bd[idx] = Lp;
    bo[idx] = out;
}

// ---------------- scan phase 2: cross-chunk combine -> carries ----------------
__global__ __launch_bounds__(256) void k_scan2(const float* __restrict__ bd,
                                               const float* __restrict__ bo,
                                               float* __restrict__ carries)
{
    int idx = blockIdx.x * 256 + threadIdx.x;   // B*D = 4096
    int d = idx & (D_-1);
    int b = idx >> 11;
    float bd0 = bd[(size_t)(b*NC_)*D_ + d];     // stab = cd[0] = bd[0] (>= -20)
    float cd = 0.f, acc = 0.f;
    #pragma unroll
    for (int c = 0; c < NC_; ++c) {
        size_t o = (size_t)(b*NC_ + c)*D_ + d;
        cd = fmaxf(cd + bd[o], -80.f);          // clip(cumsum(bd),-80,0)
        float ncd = fmaxf(cd - bd0, -20.f);     // clip(cd-stab,-20,0)
        carries[o] = acc * expf(ncd);           // sum of seeds STRICTLY BEFORE c
        acc += bo[o] * expf(-ncd);
    }
}

// ---------------- scan phase 3: recompute + carry; write state (bf16) ----------------
__global__ __launch_bounds__(256) void k_scan3(const float* __restrict__ la,
                                               const __hip_bfloat16* __restrict__ v,
                                               const float* __restrict__ carries,
                                               __hip_bfloat16* __restrict__ state)
{
    int idx = blockIdx.x * 256 + threadIdx.x;
    int d = idx & (D_-1);
    int c = (idx >> 11) & (NC_-1);
    int b = idx >> 15;
    int i = d & 63;
    const bool firstHalf = (d & 64) == 0;
    float inv = expf((float)i * (-9.210340371976184f / 64.f));
    int n0 = c * CHUNK_;
    float cs = cosf((float)n0 * inv), sn = sinf((float)n0 * inv);
    float ca = cosf(inv), sa = sinf(inv);
    float carry = carries[idx];
    size_t row0 = (size_t)b * N_ + (size_t)c * CHUNK_;
    float S = 0.f, Lp = 0.f, out = 0.f;
    #pragma unroll 8
    for (int t = 0; t < CHUNK_; ++t) {
        size_t off = (row0 + t) * (size_t)D_ + d;
        float a  = la[off];
        float vo = __bfloat162float(v[off]);
        float vp = __bfloat162float(v[firstHalf ? off + 64 : off - 64]);
        float dt = -a;
        float vin = (firstHalf ? (vo*cs - vp*sn) : (vp*sn + vo*cs)) * dt;
        S += a;
        float L = fmaxf(S, -20.f);
        out = expf(L - Lp) * out + vin;
        Lp = L;
        state[off] = __float2bfloat16(out + carry * expf(L));
        float csn = cs*ca - sn*sa;
        sn = sn*ca + cs*sa;
        cs = csn;
    }
}

// ---------------- head_mix (generic 16x16) * gate -> y (bf16) ----------------
__global__ __launch_bounds__(256) void k_headmix_gate(const __hip_bfloat16* __restrict__ state,
                                                      const __hip_bfloat16* __restrict__ gate,
                                                      const float* __restrict__ hm,
                                                      __hip_bfloat16* __restrict__ y)
{
    __shared__ float lf[D_];
    __shared__ float lhm[H_*H_];
    const int row = blockIdx.x;
    const size_t base = (size_t)row * D_;
    u16x8 s8 = ((const u16x8*)(state + base))[threadIdx.x];
    #pragma unroll
    for (int j = 0; j < 8; ++j) lf[threadIdx.x*8 + j] = bf2f(s8[j]);
    if (threadIdx.x < H_*H_) lhm[threadIdx.x] = hm[threadIdx.x];
    __syncthreads();
    #pragma unroll
    for (int k = 0; k < 8; ++k) {
        int o = threadIdx.x + k*256;
        int m  = o >> 7;
        int dh = o & 127;
        float s = 0.f;
        #pragma unroll
        for (int h = 0; h < H_; ++h) s += lf[h*DH_ + dh] * lhm[h*H_ + m];
        float g = __bfloat162float(gate[base + o]);
        y[base + o] = __float2bfloat16(s * g);
    }
}

extern "C" void kernel_launch(void* const* d_in, const int* in_sizes, int n_in,
                              void* d_out, int out_size, void* d_ws, size_t ws_size,
                              hipStream_t stream)
{
    const float* x          = (const float*)d_in[0];
    const float* norm_scale = (const float*)d_in[1];
    const float* conv_w     = (const float*)d_in[2];
    const float* conv_b     = (const float*)d_in[3];
    const float* in_proj_w  = (const float*)d_in[4];
    const float* dt_bias    = (const float*)d_in[5];
    const float* head_mix   = (const float*)d_in[6];
    const float* out_proj_w = (const float*)d_in[7];
    float* out = (float*)d_out;

    // Workspace layout — total 176,947,200 B.
    char* ws = (char*)d_ws;
    float*          la   = (float*)ws;                               // 67,108,864 B (log_alpha, f32)
    __hip_bfloat16* xn   = (__hip_bfloat16*)(ws + 67108864);         // 33,554,432 B; reused for w1 after conv
    __hip_bfloat16* xc   = (__hip_bfloat16*)(ws + 100663296);        // 33,554,432 B; reused for y after GEMM1
    __hip_bfloat16* gate = (__hip_bfloat16*)(ws + 134217728);        // 33,554,432 B
    __hip_bfloat16* w2   = (__hip_bfloat16*)(ws + 167772160);        //  8,388,608 B
    float*          bd   = (float*)(ws + 176160768);                 //    262,144 B
    float*          bo   = (float*)(ws + 176422912);                 //    262,144 B
    float*          carr = (float*)(ws + 176685056);                 //    262,144 B
    __hip_bfloat16* w1   = xn;   // xn dead after conv
    __hip_bfloat16* y    = xc;   // xc dead after GEMM1
    // d_out as staged scratch: v (bf16, first half) and state (bf16, second half),
    // both fully dead before GEMM2 overwrites d_out with the final f32 output.
    __hip_bfloat16* v     = (__hip_bfloat16*)d_out;
    __hip_bfloat16* state = (__hip_bfloat16*)((char*)d_out + 33554432);

    k_rmsnorm<<<M_, 256, 0, stream>>>(x, norm_scale, xn);
    k_conv_silu<<<(M_*(size_t)D_)/8/256, 256, 0, stream>>>(xn, conv_w, conv_b, xc);
    k_cast_bf16<<<6144, 256, 0, stream>>>(in_proj_w, w1);
    k_cast_bf16<<<2048, 256, 0, stream>>>(out_proj_w, w2);
    k_gemm<0><<<dim3(M_/128, F3D/128), 256, 0, stream>>>(xc, w1, D_, la, v, gate, dt_bias, nullptr, nullptr);
    k_scan1<<<(B_*NC_*D_)/256, 256, 0, stream>>>(la, v, bd, bo);
    k_scan2<<<(B_*D_)/256, 256, 0, stream>>>(bd, bo, carr);
    k_scan3<<<(B_*NC_*D_)/256, 256, 0, stream>>>(la, v, carr, state);
    k_headmix_gate<<<M_, 256, 0, stream>>>(state, gate, head_mix, y);
    k_gemm<1><<<dim3(M_/128, D_/128), 256, 0, stream>>>(y, w2, D_, nullptr, nullptr, nullptr, nullptr, x, out);
}